// Round 4
// baseline (6760.092 us; speedup 1.0000x reference)
//
#include <hip/hip_runtime.h>
#include <math.h>

// ============================================================================
// RSSM forward on MI355X.
// Round 4: (a) amdgpu_waves_per_eu(4,4) pins 4 waves/EU -> 128 VGPR budget so
// the batched weight-tile loads actually stay in flight (R3 showed the
// compiler capped at 64 VGPRs and re-serialized); (b) prior & posterior
// paths merged into shared phases (C: pr1||po1, D: pr2||po2, E: 4 heads)
// halving the dependent load-phase chain per step: A(gin) -> B(GRU) -> C ->
// D -> E -> sample.
// ============================================================================

using v8s   = __attribute__((ext_vector_type(8))) short;
using f32x4 = __attribute__((ext_vector_type(4))) float;

#define BN   512
#define TN   128
#define LATN 128

#define AB_S 264   // 256-col LDS activation stride (shorts)
#define SA_S 136   // 128-col stride

// pre-shuffled weight tile bases (1 tile = 16n x 32k bf16 = 1KB = 512 shorts)
#define OBS1_T 0
#define OBS2_T 256
#define PO1O_T 384
#define PO1H_T 512
#define GINS_T 640
#define IH_T   704
#define HH_T   1088
#define PR1_T  1472
#define PR2_T  1600
#define PRM_T  1728
#define PRV_T  1792
#define PO2_T  1856
#define POM_T  1984
#define POV_T  2048
#define TOT_TILES 2112

#define B1_BYTES 33554432UL          // 65536 x 256 bf16
#define KL_OFF   8388608UL           // states elements (512*128*128)

__device__ __forceinline__ unsigned short f2bf(float f){
  union { float f; unsigned u; } v; v.f = f;
  unsigned u = v.u + 0x7fffu + ((v.u >> 16) & 1u);   // RNE
  return (unsigned short)(u >> 16);
}
__device__ __forceinline__ float bf2f(unsigned short s){
  union { unsigned u; float f; } v; v.u = ((unsigned)s) << 16; return v.f;
}
__device__ __forceinline__ float sigm(float x){ return 1.f / (1.f + __expf(-x)); }
__device__ __forceinline__ float tanhx(float x){ return 1.f - 2.f/(__expf(2.f*x) + 1.f); }

#define MFMA16(a,b,c) __builtin_amdgcn_mfma_f32_16x16x32_bf16((a),(b),(c),0,0,0)
#define LDB(tIdx) (*(const v8s*)(wt + ((size_t)(tIdx))*512 + lane*8))

// ---------------------------------------------------------------------------
// Weight shuffle: f32 (N,K) row-major -> bf16 fragment-linear tiles.
// ---------------------------------------------------------------------------
struct ShufArgs {
  const float* src[14];
  int stride[14], coloff[14], ktiles[14], tbase[14], tcnt[14];
};

__global__ __launch_bounds__(64) void shuffle_w(ShufArgs sa, unsigned short* __restrict__ wt)
{
  int tile = blockIdx.x;
  int s = 0;
  while (tile >= sa.tbase[s] + sa.tcnt[s]) s++;
  int lt = tile - sa.tbase[s];
  int kt = lt % sa.ktiles[s];
  int nt = lt / sa.ktiles[s];
  int l  = threadIdx.x;
  int n  = nt*16 + (l & 15);
  int k  = sa.coloff[s] + kt*32 + (l >> 4)*8;
  const float* sp = sa.src[s] + (size_t)n * sa.stride[s] + k;
  unsigned short* dp = wt + (size_t)tile*512 + (size_t)l*8;
  #pragma unroll
  for (int j = 0; j < 8; j++) dp[j] = f2bf(sp[j]);
}

// ---------------------------------------------------------------------------
// Parallel GEMM for obs MLP / po1_o precompute.
// ---------------------------------------------------------------------------
__global__ __launch_bounds__(256) void big_gemm(
    const void* __restrict__ Ain, int aIsF32, int K,
    const unsigned short* __restrict__ wt, int tbase,
    const float* __restrict__ bias, int doRelu,
    unsigned short* __restrict__ outB)
{
  __shared__ unsigned short AL[64*AB_S];
  int tid = threadIdx.x, lane = tid & 63, wv = tid >> 6;
  int q = lane >> 4, c16 = lane & 15;
  size_t row0 = (size_t)blockIdx.x * 64;

  f32x4 acc[16];
  #pragma unroll
  for (int nt = 0; nt < 16; nt++) acc[nt] = (f32x4){0.f,0.f,0.f,0.f};

  int nchunk = K >> 8;
  int ktT    = K >> 5;
  for (int cc = 0; cc < nchunk; cc++){
    int r = tid >> 2, c0 = (tid & 3) * 64;
    if (aIsF32){
      const float* A = (const float*)Ain + (row0 + r) * (size_t)K + (size_t)cc*256 + c0;
      #pragma unroll
      for (int ii = 0; ii < 16; ii++){
        float4 x = ((const float4*)A)[ii];
        ushort4 o;
        o.x = f2bf(x.x); o.y = f2bf(x.y); o.z = f2bf(x.z); o.w = f2bf(x.w);
        *(ushort4*)&AL[r*AB_S + c0 + ii*4] = o;
      }
    } else {
      const unsigned short* A = (const unsigned short*)Ain + (row0 + r)*256 + c0;
      #pragma unroll
      for (int ii = 0; ii < 8; ii++)
        *(v8s*)&AL[r*AB_S + c0 + ii*8] = *(const v8s*)(A + ii*8);
    }
    __syncthreads();
    const unsigned short* myA = &AL[wv*16*AB_S];
    #pragma unroll
    for (int kt = 0; kt < 8; kt++){
      v8s af = *(const v8s*)&myA[c16*AB_S + kt*32 + q*8];
      #pragma unroll
      for (int nt = 0; nt < 16; nt++){
        v8s bf = *(const v8s*)(wt + ((size_t)(tbase + nt*ktT + cc*8 + kt))*512 + lane*8);
        acc[nt] = MFMA16(af, bf, acc[nt]);
      }
    }
    __syncthreads();
  }
  #pragma unroll
  for (int nt = 0; nt < 16; nt++){
    int col = nt*16 + c16;
    float b = bias[col];
    #pragma unroll
    for (int i = 0; i < 4; i++){
      float v = acc[nt][i] + b;
      if (doRelu) v = fmaxf(v, 0.f);
      outB[(row0 + wv*16 + q*4 + i)*256 + col] = f2bf(v);
    }
  }
}

// ---------------------------------------------------------------------------
// Recurrent helpers: 16 rows x 256 cols, 16 waves; wave wv owns col strip wv.
// ---------------------------------------------------------------------------
__device__ __forceinline__ void stage256(
    const unsigned short* __restrict__ inA,
    const unsigned short* __restrict__ wt, int tbase,
    const float* __restrict__ bias,
    unsigned short* __restrict__ outA, int lane, int wv)
{
  int q = lane >> 4, c16 = lane & 15;
  v8s wf[8];
  #pragma unroll
  for (int kt = 0; kt < 8; kt++) wf[kt] = LDB(tbase + wv*8 + kt);
  v8s af[8];
  #pragma unroll
  for (int kt = 0; kt < 8; kt++) af[kt] = *(const v8s*)&inA[c16*AB_S + kt*32 + q*8];
  f32x4 acc = (f32x4){0.f,0.f,0.f,0.f};
  #pragma unroll
  for (int kt = 0; kt < 8; kt++) acc = MFMA16(af[kt], wf[kt], acc);
  int col = wv*16 + c16;
  float b = bias[col];
  #pragma unroll
  for (int i = 0; i < 4; i++)
    outA[(q*4 + i)*AB_S + col] = f2bf(fmaxf(acc[i] + b, 0.f));
}

// Stage C: pr_mid1 = relu(h@PR1+b) -> AB1 ; po_mid1 = relu(h@PO1H + po1_o) -> AB3
__device__ __forceinline__ void stageC(
    const unsigned short* __restrict__ hA,
    const unsigned short* __restrict__ wt,
    const float* __restrict__ b_pr1,
    const unsigned short* __restrict__ pAdd,   // po1_o at (row r -> r*TN*256), +col
    unsigned short* __restrict__ AB1, unsigned short* __restrict__ AB3,
    int lane, int wv)
{
  int q = lane >> 4, c16 = lane & 15;
  int col = wv*16 + c16;
  v8s wfA[8], wfB[8];
  #pragma unroll
  for (int kt = 0; kt < 8; kt++) wfA[kt] = LDB(PR1_T + wv*8 + kt);
  #pragma unroll
  for (int kt = 0; kt < 8; kt++) wfB[kt] = LDB(PO1H_T + wv*8 + kt);
  unsigned short pv[4];
  #pragma unroll
  for (int i = 0; i < 4; i++)
    pv[i] = __builtin_nontemporal_load(&pAdd[(size_t)(q*4 + i)*(TN*256) + col]);
  v8s af[8];
  #pragma unroll
  for (int kt = 0; kt < 8; kt++) af[kt] = *(const v8s*)&hA[c16*AB_S + kt*32 + q*8];
  f32x4 aA = (f32x4){0.f,0.f,0.f,0.f}, aB = (f32x4){0.f,0.f,0.f,0.f};
  #pragma unroll
  for (int kt = 0; kt < 8; kt++){
    aA = MFMA16(af[kt], wfA[kt], aA);
    aB = MFMA16(af[kt], wfB[kt], aB);
  }
  float b1 = b_pr1[col];
  #pragma unroll
  for (int i = 0; i < 4; i++){
    AB1[(q*4 + i)*AB_S + col] = f2bf(fmaxf(aA[i] + b1, 0.f));
    AB3[(q*4 + i)*AB_S + col] = f2bf(fmaxf(aB[i] + bf2f(pv[i]), 0.f));
  }
}

// Stage D: pr_mid2 = relu(AB1@PR2+b) -> AB2 ; po_mid2 = relu(AB3@PO2+b) -> AB4
__device__ __forceinline__ void stageD(
    const unsigned short* __restrict__ AB1, const unsigned short* __restrict__ AB3,
    const unsigned short* __restrict__ wt,
    const float* __restrict__ b_pr2, const float* __restrict__ b_po2,
    unsigned short* __restrict__ AB2, unsigned short* __restrict__ AB4,
    int lane, int wv)
{
  int q = lane >> 4, c16 = lane & 15;
  int col = wv*16 + c16;
  v8s wfA[8], wfB[8];
  #pragma unroll
  for (int kt = 0; kt < 8; kt++) wfA[kt] = LDB(PR2_T + wv*8 + kt);
  #pragma unroll
  for (int kt = 0; kt < 8; kt++) wfB[kt] = LDB(PO2_T + wv*8 + kt);
  v8s af0[8];
  #pragma unroll
  for (int kt = 0; kt < 8; kt++) af0[kt] = *(const v8s*)&AB1[c16*AB_S + kt*32 + q*8];
  f32x4 aA = (f32x4){0.f,0.f,0.f,0.f};
  #pragma unroll
  for (int kt = 0; kt < 8; kt++) aA = MFMA16(af0[kt], wfA[kt], aA);
  v8s af1[8];
  #pragma unroll
  for (int kt = 0; kt < 8; kt++) af1[kt] = *(const v8s*)&AB3[c16*AB_S + kt*32 + q*8];
  f32x4 aB = (f32x4){0.f,0.f,0.f,0.f};
  #pragma unroll
  for (int kt = 0; kt < 8; kt++) aB = MFMA16(af1[kt], wfB[kt], aB);
  float bA = b_pr2[col], bB = b_po2[col];
  #pragma unroll
  for (int i = 0; i < 4; i++){
    AB2[(q*4 + i)*AB_S + col] = f2bf(fmaxf(aA[i] + bA, 0.f));
    AB4[(q*4 + i)*AB_S + col] = f2bf(fmaxf(aB[i] + bB, 0.f));
  }
}

// Stage E: all four heads. Wave wv: prior head task (wv) + posterior task (wv).
// task: mtx = wv>>3 (0=mu,1=var), nt = wv&7.
__device__ __forceinline__ void stageE(
    const unsigned short* __restrict__ AB2, const unsigned short* __restrict__ AB4,
    const unsigned short* __restrict__ wt,
    const float* __restrict__ b_prm, const float* __restrict__ b_prv,
    const float* __restrict__ b_pom, const float* __restrict__ b_pov,
    float* __restrict__ mupF, float* __restrict__ varpF,
    float* __restrict__ muqF, float* __restrict__ varqF,
    int lane, int wv)
{
  int q = lane >> 4, c16 = lane & 15;
  int isv = wv >> 3, nt = wv & 7;
  int col = nt*16 + c16;
  v8s wf0[8], wf1[8];
  #pragma unroll
  for (int kt = 0; kt < 8; kt++) wf0[kt] = LDB((isv ? PRV_T : PRM_T) + nt*8 + kt);
  #pragma unroll
  for (int kt = 0; kt < 8; kt++) wf1[kt] = LDB((isv ? POV_T : POM_T) + nt*8 + kt);
  v8s af[8];
  #pragma unroll
  for (int kt = 0; kt < 8; kt++) af[kt] = *(const v8s*)&AB2[c16*AB_S + kt*32 + q*8];
  f32x4 a0 = (f32x4){0.f,0.f,0.f,0.f};
  #pragma unroll
  for (int kt = 0; kt < 8; kt++) a0 = MFMA16(af[kt], wf0[kt], a0);
  #pragma unroll
  for (int kt = 0; kt < 8; kt++) af[kt] = *(const v8s*)&AB4[c16*AB_S + kt*32 + q*8];
  f32x4 a1 = (f32x4){0.f,0.f,0.f,0.f};
  #pragma unroll
  for (int kt = 0; kt < 8; kt++) a1 = MFMA16(af[kt], wf1[kt], a1);
  float bp = isv ? b_prv[col] : b_prm[col];
  float bq = isv ? b_pov[col] : b_pom[col];
  #pragma unroll
  for (int i = 0; i < 4; i++){
    int r = q*4 + i;
    float v0 = a0[i] + bp, v1 = a1[i] + bq;
    if (isv){
      varpF[r*LATN + col] = __expf(v0) + 0.01f;
      varqF[r*LATN + col] = __expf(v1) + 0.01f;
    } else {
      mupF[r*LATN + col] = v0;
      muqF[r*LATN + col] = v1;
    }
  }
}

// s0 heads: posterior only, from AB4.
__device__ __forceinline__ void headsS0(
    const unsigned short* __restrict__ AB4,
    const unsigned short* __restrict__ wt,
    const float* __restrict__ b_pom, const float* __restrict__ b_pov,
    float* __restrict__ muqF, float* __restrict__ varqF, int lane, int wv)
{
  int q = lane >> 4, c16 = lane & 15;
  int isv = wv >> 3, nt = wv & 7;
  int col = nt*16 + c16;
  v8s wf[8];
  #pragma unroll
  for (int kt = 0; kt < 8; kt++) wf[kt] = LDB((isv ? POV_T : POM_T) + nt*8 + kt);
  v8s af[8];
  #pragma unroll
  for (int kt = 0; kt < 8; kt++) af[kt] = *(const v8s*)&AB4[c16*AB_S + kt*32 + q*8];
  f32x4 a = (f32x4){0.f,0.f,0.f,0.f};
  #pragma unroll
  for (int kt = 0; kt < 8; kt++) a = MFMA16(af[kt], wf[kt], a);
  float b = isv ? b_pov[col] : b_pom[col];
  #pragma unroll
  for (int i = 0; i < 4; i++){
    int r = q*4 + i;
    float v = a[i] + b;
    if (isv) varqF[r*LATN + col] = __expf(v) + 0.01f;
    else     muqF [r*LATN + col] = v;
  }
}

// ---------------------------------------------------------------------------
// Persistent recurrence: block g owns batch rows g*16..g*16+15 for all steps.
// 1024 threads = 16 waves; amdgpu_waves_per_eu(4,4) pins exactly 4 waves/EU
// -> 128-VGPR budget so batched tile loads stay in flight.
// ---------------------------------------------------------------------------
__global__ __launch_bounds__(1024)
__attribute__((amdgpu_waves_per_eu(4, 4)))
void rssm_rnn(
    const unsigned short* __restrict__ wt,
    const unsigned short* __restrict__ Pbuf,      // po1_o bf16 (B*T x 256)
    const float* __restrict__ actions, const float* __restrict__ noise,
    const float* __restrict__ w_gin,  const float* __restrict__ b_gin,
    const float* __restrict__ b_ih,   const float* __restrict__ b_hh,
    const float* __restrict__ b_pr1,  const float* __restrict__ b_pr2,
    const float* __restrict__ b_prm,  const float* __restrict__ b_prv,
    const float* __restrict__ b_po2,  const float* __restrict__ b_pom,
    const float* __restrict__ b_pov,
    float* __restrict__ out)
{
  __shared__ unsigned short sA [16*SA_S];
  __shared__ unsigned short hA [16*AB_S];
  __shared__ unsigned short AB1[16*AB_S];   // pr_mid1 ; overlaid muq (f32)
  __shared__ unsigned short AB2[16*AB_S];   // pr_mid2
  __shared__ unsigned short AB3[16*AB_S];   // po_mid1 ; overlaid varq (f32)
  __shared__ unsigned short AB4[16*AB_S];   // po_mid2
  __shared__ float hF   [16*256];
  __shared__ float mupF [16*LATN];
  __shared__ float varpF[16*LATN];
  __shared__ float aF   [16*8];

  float* muqF  = (float*)AB1;
  float* varqF = (float*)AB3;

  int tid = threadIdx.x, lane = tid & 63, wv = tid >> 6;
  int q = lane >> 4, c16 = lane & 15;
  int b0 = blockIdx.x * 16;

  for (int i = tid; i < 16*256; i += 1024) hF[i] = 0.f;
  for (int i = tid; i < 16*AB_S; i += 1024) hA[i] = 0;

  // ---- s0: posterior with belief = 0 -> po_mid1 = relu(po1_o[:, t=0]) ----
  for (int i = tid; i < 16*256; i += 1024){
    int r = i >> 8, c = i & 255;
    float v = bf2f(__builtin_nontemporal_load(&Pbuf[((size_t)(b0 + r)*TN + 0)*256 + c]));
    AB3[r*AB_S + c] = f2bf(fmaxf(v, 0.f));
  }
  __syncthreads();
  stage256(AB3, wt, PO2_T, b_po2, AB4, lane, wv);
  __syncthreads();
  headsS0(AB4, wt, b_pom, b_pov, muqF, varqF, lane, wv);
  __syncthreads();
  {
    int r = wv;
    #pragma unroll
    for (int ii = 0; ii < 2; ii++){
      int c = lane + ii*64;
      float mq = muqF[r*LATN + c], vq = varqF[r*LATN + c];
      float ep = __builtin_nontemporal_load(&noise[((size_t)0*BN + b0 + r)*LATN + c]);
      float sv = mq + sqrtf(vq)*ep;
      sA[r*SA_S + c] = f2bf(sv);
      __builtin_nontemporal_store(sv, &out[((size_t)(b0 + r)*TN + 0)*LATN + c]);
    }
  }
  __syncthreads();

  for (int t = 0; t < TN-1; t++){
    if (tid < 128)
      aF[tid] = __builtin_nontemporal_load(
          &actions[((size_t)(b0 + (tid>>3))*127 + t)*8 + (tid & 7)]);
    __syncthreads();

    // ---- A: g = relu(s @ WginS^T + a @ WginA^T + b_gin) -> AB2 (temp) ----
    {
      v8s wf[4];
      #pragma unroll
      for (int kt = 0; kt < 4; kt++) wf[kt] = LDB(GINS_T + wv*4 + kt);
      v8s af[4];
      #pragma unroll
      for (int kt = 0; kt < 4; kt++) af[kt] = *(const v8s*)&sA[c16*SA_S + kt*32 + q*8];
      int col = wv*16 + c16;
      float bg = b_gin[col];
      float wa[8];
      #pragma unroll
      for (int j = 0; j < 8; j++) wa[j] = w_gin[col*136 + 128 + j];
      f32x4 acc = (f32x4){0.f,0.f,0.f,0.f};
      #pragma unroll
      for (int kt = 0; kt < 4; kt++) acc = MFMA16(af[kt], wf[kt], acc);
      #pragma unroll
      for (int i = 0; i < 4; i++){
        int r = q*4 + i;
        float v = acc[i] + bg;
        #pragma unroll
        for (int j = 0; j < 8; j++) v += aF[r*8 + j]*wa[j];
        AB2[r*AB_S + col] = f2bf(fmaxf(v, 0.f));
      }
    }
    __syncthreads();

    // ---- B: fused GRU (g in AB2, old h in hA) ----
    float hnew[4];
    {
      int col = wv*16 + c16;
      f32x4 accI[3];
      {
        v8s ag[8];
        #pragma unroll
        for (int kt = 0; kt < 8; kt++) ag[kt] = *(const v8s*)&AB2[c16*AB_S + kt*32 + q*8];
        #pragma unroll
        for (int s = 0; s < 3; s++){
          v8s wf[8];
          #pragma unroll
          for (int kt = 0; kt < 8; kt++) wf[kt] = LDB(IH_T + (s*16 + wv)*8 + kt);
          accI[s] = (f32x4){0.f,0.f,0.f,0.f};
          #pragma unroll
          for (int kt = 0; kt < 8; kt++) accI[s] = MFMA16(ag[kt], wf[kt], accI[s]);
        }
      }
      float rg[4], zg[4];
      {
        v8s ah[8];
        #pragma unroll
        for (int kt = 0; kt < 8; kt++) ah[kt] = *(const v8s*)&hA[c16*AB_S + kt*32 + q*8];
        // r and z batched together: 16 tiles in flight
        {
          v8s wfr[8], wfz[8];
          #pragma unroll
          for (int kt = 0; kt < 8; kt++) wfr[kt] = LDB(HH_T + (0*16 + wv)*8 + kt);
          #pragma unroll
          for (int kt = 0; kt < 8; kt++) wfz[kt] = LDB(HH_T + (1*16 + wv)*8 + kt);
          f32x4 ar = (f32x4){0.f,0.f,0.f,0.f}, az = (f32x4){0.f,0.f,0.f,0.f};
          #pragma unroll
          for (int kt = 0; kt < 8; kt++){
            ar = MFMA16(ah[kt], wfr[kt], ar);
            az = MFMA16(ah[kt], wfz[kt], az);
          }
          float bir = b_ih[col], bhr = b_hh[col];
          float biz = b_ih[256+col], bhz = b_hh[256+col];
          #pragma unroll
          for (int i = 0; i < 4; i++){
            rg[i] = sigm(accI[0][i] + bir + ar[i] + bhr);
            zg[i] = sigm(accI[1][i] + biz + az[i] + bhz);
          }
        }
        {
          v8s wfn[8];
          #pragma unroll
          for (int kt = 0; kt < 8; kt++) wfn[kt] = LDB(HH_T + (2*16 + wv)*8 + kt);
          f32x4 an = (f32x4){0.f,0.f,0.f,0.f};
          #pragma unroll
          for (int kt = 0; kt < 8; kt++) an = MFMA16(ah[kt], wfn[kt], an);
          float bin = b_ih[512+col], bhn = b_hh[512+col];
          #pragma unroll
          for (int i = 0; i < 4; i++){
            int r = q*4 + i;
            float ng = tanhx(accI[2][i] + bin + rg[i]*(an[i] + bhn));
            float ho = hF[r*256 + col];
            float hv = (1.f - zg[i])*ng + zg[i]*ho;
            hF[r*256 + col] = hv;
            hnew[i] = hv;
          }
        }
      }
    }
    __syncthreads();   // all waves' ah reads done before hA is overwritten
    {
      int col = wv*16 + c16;
      #pragma unroll
      for (int i = 0; i < 4; i++) hA[(q*4 + i)*AB_S + col] = f2bf(hnew[i]);
    }
    __syncthreads();

    // ---- C: pr_mid1 -> AB1 ; po_mid1 -> AB3 ----
    stageC(hA, wt, b_pr1, Pbuf + ((size_t)b0*TN + (t+1))*256, AB1, AB3, lane, wv);
    __syncthreads();

    // ---- D: pr_mid2 -> AB2 ; po_mid2 -> AB4 ----
    stageD(AB1, AB3, wt, b_pr2, b_po2, AB2, AB4, lane, wv);
    __syncthreads();

    // ---- E: 4 heads (AB2 -> mup/varp ; AB4 -> muq/varq over AB1/AB3) ----
    stageE(AB2, AB4, wt, b_prm, b_prv, b_pom, b_pov,
           mupF, varpF, muqF, varqF, lane, wv);
    __syncthreads();

    // ---- sample + KL: wave wv owns batch row wv ----
    {
      int r = wv;
      float kv = 0.f;
      #pragma unroll
      for (int ii = 0; ii < 2; ii++){
        int c = lane + ii*64;
        float mq = muqF[r*LATN + c], vq = varqF[r*LATN + c];
        float ep = __builtin_nontemporal_load(
            &noise[((size_t)(t+1)*BN + b0 + r)*LATN + c]);
        float sv = mq + sqrtf(vq)*ep;
        sA[r*SA_S + c] = f2bf(sv);
        __builtin_nontemporal_store(sv, &out[((size_t)(b0 + r)*TN + (t+1))*LATN + c]);
        float mp = mupF[r*LATN + c], vp = varpF[r*LATN + c];
        float d = mq - mp;
        kv += __logf(vp) - __logf(vq) + (vq + d*d)/vp - 1.f;
      }
      #pragma unroll
      for (int m = 1; m < 64; m <<= 1) kv += __shfl_xor(kv, m, 64);
      if (lane == 0)
        __builtin_nontemporal_store(0.5f*kv, &out[KL_OFF + (size_t)(b0 + r)*127 + t]);
    }
    __syncthreads();
  }
}

// ---------------------------------------------------------------------------
extern "C" void kernel_launch(void* const* d_in, const int* in_sizes, int n_in,
                              void* d_out, int out_size, void* d_ws, size_t ws_size,
                              hipStream_t stream)
{
  (void)in_sizes; (void)n_in; (void)out_size; (void)ws_size;
  const float* vis    = (const float*)d_in[0];
  const float* acts   = (const float*)d_in[1];
  const float* noise  = (const float*)d_in[2];
  const float* w_obs1 = (const float*)d_in[3];
  const float* b_obs1 = (const float*)d_in[4];
  const float* w_obs2 = (const float*)d_in[5];
  const float* b_obs2 = (const float*)d_in[6];
  const float* w_gin  = (const float*)d_in[7];
  const float* b_gin  = (const float*)d_in[8];
  const float* w_ih   = (const float*)d_in[9];
  const float* w_hh   = (const float*)d_in[10];
  const float* b_ih   = (const float*)d_in[11];
  const float* b_hh   = (const float*)d_in[12];
  const float* w_pr1  = (const float*)d_in[13];
  const float* b_pr1  = (const float*)d_in[14];
  const float* w_pr2  = (const float*)d_in[15];
  const float* b_pr2  = (const float*)d_in[16];
  const float* w_prm  = (const float*)d_in[17];
  const float* b_prm  = (const float*)d_in[18];
  const float* w_prv  = (const float*)d_in[19];
  const float* b_prv  = (const float*)d_in[20];
  const float* w_po1  = (const float*)d_in[21];
  const float* b_po1  = (const float*)d_in[22];
  const float* w_po2  = (const float*)d_in[23];
  const float* b_po2  = (const float*)d_in[24];
  const float* w_pom  = (const float*)d_in[25];
  const float* b_pom  = (const float*)d_in[26];
  const float* w_pov  = (const float*)d_in[27];
  const float* b_pov  = (const float*)d_in[28];

  unsigned short* B1 = (unsigned short*)d_ws;                       // 65536x256 bf16
  unsigned short* WT = (unsigned short*)((char*)d_ws + B1_BYTES);   // shuffled tiles

  ShufArgs sa;
  const float* srcs[14] = {w_obs1, w_obs2, w_po1, w_po1, w_gin, w_ih, w_hh,
                           w_pr1, w_pr2, w_prm, w_prv, w_po2, w_pom, w_pov};
  const int strides[14] = {512,256,512,512,136,256,256,256,256,256,256,256,256,256};
  const int coloffs[14] = {0,0,256,0,0,0,0,0,0,0,0,0,0,0};
  const int ktl[14]     = {16,8,8,8,4,8,8,8,8,8,8,8,8,8};
  const int tbas[14]    = {OBS1_T,OBS2_T,PO1O_T,PO1H_T,GINS_T,IH_T,HH_T,
                           PR1_T,PR2_T,PRM_T,PRV_T,PO2_T,POM_T,POV_T};
  const int tcnt[14]    = {256,128,128,128,64,384,384,128,128,64,64,128,64,64};
  for (int i = 0; i < 14; i++){
    sa.src[i] = srcs[i]; sa.stride[i] = strides[i]; sa.coloff[i] = coloffs[i];
    sa.ktiles[i] = ktl[i]; sa.tbase[i] = tbas[i]; sa.tcnt[i] = tcnt[i];
  }
  shuffle_w<<<TOT_TILES, 64, 0, stream>>>(sa, WT);

  // obs MLP + po1_o, all in-place in B1 (rows are block-exclusive)
  big_gemm<<<1024, 256, 0, stream>>>(vis, 1, 512, WT, OBS1_T, b_obs1, 1, B1);
  big_gemm<<<1024, 256, 0, stream>>>(B1,  0, 256, WT, OBS2_T, b_obs2, 1, B1);
  big_gemm<<<1024, 256, 0, stream>>>(B1,  0, 256, WT, PO1O_T, b_po1,  0, B1);

  rssm_rnn<<<32, 1024, 0, stream>>>(WT, B1, acts, noise, w_gin, b_gin, b_ih, b_hh,
                                    b_pr1, b_pr2, b_prm, b_prv, b_po2, b_pom, b_pov,
                                    (float*)d_out);
}